// Round 1
// baseline (244.990 us; speedup 1.0000x reference)
//
#include <hip/hip_runtime.h>
#include <math.h>

#define NROWS 1546
#define INDIM 1546
#define ODIM  64
#define NDRUG 1373
#define MINN  1e-15f
#define MAXNRM 0.996f   // (1 - 4e-3)/sqrt(c), c=1

__device__ __forceinline__ float artanh_(float x) {
    x = fminf(fmaxf(x, -1.0f + 1e-7f), 1.0f - 1e-7f);
    return 0.5f * (log1pf(x) - log1pf(-x));
}

__device__ __forceinline__ float wsum(float v) {
#pragma unroll
    for (int off = 32; off > 0; off >>= 1) v += __shfl_xor(v, off, 64);
    return v;
}

// ---- kernel 0: transpose W[64][1546] -> Wt[1546][64] (both matrices) ----
__global__ void prep_kernel(const float* __restrict__ Wd, const float* __restrict__ Wm,
                            float* __restrict__ WtD, float* __restrict__ WtM) {
    int total = ODIM * INDIM;
    for (int i = blockIdx.x * blockDim.x + threadIdx.x; i < total; i += gridDim.x * blockDim.x) {
        int o = i / INDIM;
        int k = i - o * INDIM;
        WtD[k * ODIM + o] = Wd[i];
        WtM[k * ODIM + o] = Wm[i];
    }
}

// ---- kernel 1: hyp_bias = proj(expmap0(bias)) for both biases, plus |hb|^2 ----
__global__ void bias_kernel(const float* __restrict__ bd, const float* __restrict__ bm,
                            float* __restrict__ hbD, float* __restrict__ hbM,
                            float* __restrict__ hb2) {
    int wave = threadIdx.x >> 6;   // blockDim = 128 -> wave 0: drug, wave 1: micr
    int lane = threadIdx.x & 63;
    const float* b = wave ? bm : bd;
    float v = b[lane];
    float un2 = wsum(v * v);
    float un = fmaxf(sqrtf(un2), MINN);
    float e = tanhf(un) * v / un;          // expmap0, sc=1
    float en2 = wsum(e * e);
    float en = fmaxf(sqrtf(en2), MINN);
    float scl = (en > MAXNRM) ? (MAXNRM / en) : 1.0f;
    e *= scl;
    float hb2v = en2 * scl * scl;
    float* hb = wave ? hbM : hbD;
    hb[lane] = e;
    if (lane == 0) hb2[wave] = hb2v;
}

// ---- kernel 2: liner_h = proj(mobius_add(proj(mobius_matvec(W,x)), hb)); xtan = logmap0 ----
#define ROWS 8
__global__ __launch_bounds__(256) void liner_kernel(
    const float* __restrict__ X, const float* __restrict__ WtD, const float* __restrict__ WtM,
    const float* __restrict__ hbD, const float* __restrict__ hbM, const float* __restrict__ hb2v,
    float* __restrict__ liner, float* __restrict__ xtan) {
    __shared__ float xs[ROWS][INDIM];
    int tid = threadIdx.x;
    int wave = tid >> 6, lane = tid & 63;
    int row0 = blockIdx.x * ROWS;

    for (int r = 0; r < ROWS; ++r) {
        int gr = min(row0 + r, NROWS - 1);
        const float* src = X + (size_t)gr * INDIM;
        for (int c = tid; c < INDIM; c += 256) xs[r][c] = src[c];
    }
    __syncthreads();

    int r0 = wave, r1 = wave + 4;
    int g0 = row0 + r0, g1 = row0 + r1;

    // per-row squared norms of x (redundant across lanes after wsum)
    float xn2[2];
    {
        float s0 = 0.f, s1 = 0.f;
        for (int k = lane; k < INDIM; k += 64) {
            float a = xs[r0][k]; s0 = fmaf(a, a, s0);
            float b = xs[r1][k]; s1 = fmaf(b, b, s1);
        }
        xn2[0] = wsum(s0);
        xn2[1] = wsum(s1);
    }

    const float* Wt0 = (g0 < NDRUG) ? WtD : WtM;
    const float* Wt1 = (g1 < NDRUG) ? WtD : WtM;
    float acc0 = 0.f, acc1 = 0.f;
    if (Wt0 == Wt1) {
        const float* p = Wt0 + lane;
#pragma unroll 8
        for (int k = 0; k < INDIM; ++k) {
            float w = p[k * 64];
            acc0 = fmaf(xs[r0][k], w, acc0);
            acc1 = fmaf(xs[r1][k], w, acc1);
        }
    } else {
        const float* p0 = Wt0 + lane;
        const float* p1 = Wt1 + lane;
#pragma unroll 8
        for (int k = 0; k < INDIM; ++k) {
            acc0 = fmaf(xs[r0][k], p0[k * 64], acc0);
            acc1 = fmaf(xs[r1][k], p1[k * 64], acc1);
        }
    }

    float accs[2] = {acc0, acc1};
    int grows[2] = {g0, g1};
#pragma unroll
    for (int j = 0; j < 2; ++j) {
        int grow = grows[j];
        if (grow < NROWS) {               // wave-uniform guard
            float mx = accs[j];
            float mxn2 = wsum(mx * mx);
            float xn = fmaxf(sqrtf(xn2[j]), MINN);
            float mxn = fmaxf(sqrtf(mxn2), MINN);
            float g = mxn / xn * artanh_(xn);
            float res = tanhf(g) * mx / mxn;
            // proj
            float rn2 = wsum(res * res);
            float rn = fmaxf(sqrtf(rn2), MINN);
            if (rn > MAXNRM) res *= MAXNRM / rn;
            // mobius_add with hyp_bias (c=1)
            const float* hb = (grow < NDRUG) ? hbD : hbM;
            float y = hb[lane];
            float y2 = hb2v[(grow < NDRUG) ? 0 : 1];
            float x2 = wsum(res * res);
            float xy = wsum(res * y);
            float num = (1.0f + 2.0f * xy + y2) * res + (1.0f - x2) * y;
            float den = 1.0f + 2.0f * xy + x2 * y2;
            float v = num / fmaxf(den, MINN);
            // proj
            float v2 = wsum(v * v);
            float vn = fmaxf(sqrtf(v2), MINN);
            if (vn > MAXNRM) { v *= MAXNRM / vn; vn = MAXNRM; }
            // logmap0
            float pn = fmaxf(vn, MINN);
            float xt = artanh_(pn) / pn * v;
            liner[(size_t)grow * ODIM + lane] = v;
            xtan[(size_t)grow * ODIM + lane] = xt;
        }
    }
}

// ---- kernel 3: support = adj @ xtan; agg = proj(expmap0(support)); gated HypAct -> h ----
__global__ __launch_bounds__(256) void agg_kernel(
    const float* __restrict__ ADJ, const float* __restrict__ xtan,
    const float* __restrict__ liner, const float* __restrict__ WN /*[128][64]*/,
    const float* __restrict__ biasnode, float* __restrict__ out_h) {
    __shared__ float as[ROWS][INDIM];
    __shared__ float zl[ROWS][128];
    int tid = threadIdx.x;
    int wave = tid >> 6, lane = tid & 63;
    int row0 = blockIdx.x * ROWS;

    for (int r = 0; r < ROWS; ++r) {
        int gr = min(row0 + r, NROWS - 1);
        const float* src = ADJ + (size_t)gr * INDIM;
        for (int c = tid; c < INDIM; c += 256) as[r][c] = src[c];
    }
    __syncthreads();

    int r0 = wave, r1 = wave + 4;
    int g0 = row0 + r0, g1 = row0 + r1;

    float acc0 = 0.f, acc1 = 0.f;
    {
        const float* p = xtan + lane;
#pragma unroll 8
        for (int k = 0; k < INDIM; ++k) {
            float w = p[k * 64];
            acc0 = fmaf(as[r0][k], w, acc0);
            acc1 = fmaf(as[r1][k], w, acc1);
        }
    }

    float accs[2] = {acc0, acc1};
    int grows[2] = {g0, g1};
    int rr[2] = {r0, r1};
    float aggv[2], linv[2];
#pragma unroll
    for (int j = 0; j < 2; ++j) {
        int grow = grows[j];
        if (grow < NROWS) {
            float s = accs[j];
            float sn2 = wsum(s * s);
            float sn = fmaxf(sqrtf(sn2), MINN);
            float agg = tanhf(sn) * s / sn;        // expmap0
            float an2 = wsum(agg * agg);
            float an = fmaxf(sqrtf(an2), MINN);
            if (an > MAXNRM) agg *= MAXNRM / an;   // proj
            float lin = liner[(size_t)grow * ODIM + lane];
            aggv[j] = agg; linv[j] = lin;
            zl[rr[j]][lane] = agg;
            zl[rr[j]][64 + lane] = lin;
        }
    }
    __syncthreads();
#pragma unroll
    for (int j = 0; j < 2; ++j) {
        int grow = grows[j];
        if (grow < NROWS) {
            float d = biasnode[grow];
            const float* w = WN + lane;
#pragma unroll 8
            for (int f = 0; f < 128; ++f) d = fmaf(zl[rr[j]][f], w[f * 64], d);
            d = fmaxf(d, 0.0f);                    // relu
            float h = d * aggv[j] + (1.0f - d) * linv[j];
            out_h[(size_t)grow * ODIM + lane] = h;
        }
    }
}

// ---- kernel 4: copy adj into second tuple output ----
__global__ void copy_adj(const float4* __restrict__ src, float4* __restrict__ dst, int n4) {
    for (int i = blockIdx.x * blockDim.x + threadIdx.x; i < n4; i += gridDim.x * blockDim.x)
        dst[i] = src[i];
}

extern "C" void kernel_launch(void* const* d_in, const int* in_sizes, int n_in,
                              void* d_out, int out_size, void* d_ws, size_t ws_size,
                              hipStream_t stream) {
    const float* x   = (const float*)d_in[0];
    const float* adj = (const float*)d_in[1];
    const float* Wd  = (const float*)d_in[2];
    const float* Wm  = (const float*)d_in[3];
    const float* bd  = (const float*)d_in[4];
    const float* bm  = (const float*)d_in[5];
    const float* wn  = (const float*)d_in[6];
    const float* bn  = (const float*)d_in[7];
    float* out = (float*)d_out;
    float* ws  = (float*)d_ws;

    const int WELEMS = ODIM * INDIM;      // 98944
    float* WtD   = ws;
    float* WtM   = ws + WELEMS;
    float* hbD   = ws + 2 * WELEMS;       // 64
    float* hbM   = hbD + 64;              // 64
    float* hb2   = hbM + 64;              // 2
    float* liner = ws + 2 * WELEMS + 192; // aligned-ish
    float* xtan  = liner + (size_t)NROWS * ODIM;

    prep_kernel<<<387, 256, 0, stream>>>(Wd, Wm, WtD, WtM);
    bias_kernel<<<1, 128, 0, stream>>>(bd, bm, hbD, hbM, hb2);

    int nblk = (NROWS + ROWS - 1) / ROWS; // 194
    liner_kernel<<<nblk, 256, 0, stream>>>(x, WtD, WtM, hbD, hbM, hb2, liner, xtan);
    agg_kernel<<<nblk, 256, 0, stream>>>(adj, xtan, liner, wn, bn, out);

    int n4 = (NROWS * NROWS) / 4;         // 597529
    copy_adj<<<(n4 + 255) / 256, 256, 0, stream>>>((const float4*)adj,
                                                   (float4*)(out + (size_t)NROWS * ODIM), n4);
}

// Round 2
// 82.086 us; speedup vs baseline: 2.9846x; 2.9846x over previous
//
#include <hip/hip_runtime.h>
#include <math.h>

#define NROWS 1546
#define INDIM 1546
#define ODIM  64
#define NDRUG 1373
#define MINN  1e-15f
#define MAXNRM 0.996f   // (1 - 4e-3)/sqrt(c), c=1

#define ROWS 4
#define XSTR 1548       // padded row stride (16B-aligned rows: 1548*4 % 16 == 0)
#define NWAVE 8
#define CHUNK 196       // 4-aligned K-chunk per wave; wave 7 gets 174

__device__ __forceinline__ float artanh_(float x) {
    x = fminf(fmaxf(x, -1.0f + 1e-7f), 1.0f - 1e-7f);
    return 0.5f * (log1pf(x) - log1pf(-x));
}

__device__ __forceinline__ float wsum(float v) {
#pragma unroll
    for (int off = 32; off > 0; off >>= 1) v += __shfl_xor(v, off, 64);
    return v;
}

// ---- kernel 0: transpose W[64][1546] -> Wt[1546][64] (both matrices) ----
__global__ void prep_kernel(const float* __restrict__ Wd, const float* __restrict__ Wm,
                            float* __restrict__ WtD, float* __restrict__ WtM) {
    int total = ODIM * INDIM;
    for (int i = blockIdx.x * blockDim.x + threadIdx.x; i < total; i += gridDim.x * blockDim.x) {
        int o = i / INDIM;
        int k = i - o * INDIM;
        WtD[k * ODIM + o] = Wd[i];
        WtM[k * ODIM + o] = Wm[i];
    }
}

// ---- kernel 1: hyp_bias = proj(expmap0(bias)), plus |hb|^2 ----
__global__ void bias_kernel(const float* __restrict__ bd, const float* __restrict__ bm,
                            float* __restrict__ hbD, float* __restrict__ hbM,
                            float* __restrict__ hb2) {
    int wave = threadIdx.x >> 6;
    int lane = threadIdx.x & 63;
    const float* b = wave ? bm : bd;
    float v = b[lane];
    float un2 = wsum(v * v);
    float un = fmaxf(sqrtf(un2), MINN);
    float e = tanhf(un) * v / un;
    float en2 = wsum(e * e);
    float en = fmaxf(sqrtf(en2), MINN);
    float scl = (en > MAXNRM) ? (MAXNRM / en) : 1.0f;
    e *= scl;
    float* hb = wave ? hbM : hbD;
    hb[lane] = e;
    if (lane == 0) hb2[wave] = en2 * scl * scl;
}

// ---- kernel 2: liner_h + xtan, K-split across 8 waves ----
__global__ __launch_bounds__(512) void liner_kernel(
    const float* __restrict__ X, const float* __restrict__ WtD, const float* __restrict__ WtM,
    const float* __restrict__ hbD, const float* __restrict__ hbM, const float* __restrict__ hb2v,
    float* __restrict__ liner, float* __restrict__ xtan) {
    __shared__ __align__(16) float xs[ROWS * XSTR];
    __shared__ float part[NWAVE][ROWS][64];
    __shared__ float xnps[NWAVE][ROWS];
    int tid = threadIdx.x;
    int wave = tid >> 6, lane = tid & 63;
    int row0 = blockIdx.x * ROWS;

    // stage 4 rows (float2: row base is 8B aligned)
    for (int r = 0; r < ROWS; ++r) {
        int gr = min(row0 + r, NROWS - 1);
        const float2* src = (const float2*)(X + (size_t)gr * INDIM);
        float2* dst = (float2*)&xs[r * XSTR];
        for (int c = tid; c < INDIM / 2; c += 512) dst[c] = src[c];
    }
    __syncthreads();

    int k0 = wave * CHUNK;
    int k1 = min(k0 + CHUNK, INDIM);

    // per-wave partial squared norms of x rows (lane-strided over chunk)
    {
        float p[ROWS] = {0.f, 0.f, 0.f, 0.f};
        for (int k = k0 + lane; k < k1; k += 64) {
#pragma unroll
            for (int r = 0; r < ROWS; ++r) { float a = xs[r * XSTR + k]; p[r] = fmaf(a, a, p[r]); }
        }
#pragma unroll
        for (int r = 0; r < ROWS; ++r) {
            float s = wsum(p[r]);
            if (lane == 0) xnps[wave][r] = s;
        }
    }

    // K-chunk GEMM: 4 rows x 64 outs
    float acc[ROWS] = {0.f, 0.f, 0.f, 0.f};
    bool uniform = ((row0 < NDRUG) == (row0 + ROWS - 1 < NDRUG));
    if (uniform) {
        const float* wp = ((row0 < NDRUG) ? WtD : WtM) + lane;
        int k = k0;
        for (; k + 4 <= k1; k += 4) {
            float w0 = wp[(k + 0) * 64];
            float w1 = wp[(k + 1) * 64];
            float w2 = wp[(k + 2) * 64];
            float w3 = wp[(k + 3) * 64];
#pragma unroll
            for (int r = 0; r < ROWS; ++r) {
                float4 xv = *(const float4*)(xs + r * XSTR + k);
                acc[r] = fmaf(xv.x, w0, acc[r]);
                acc[r] = fmaf(xv.y, w1, acc[r]);
                acc[r] = fmaf(xv.z, w2, acc[r]);
                acc[r] = fmaf(xv.w, w3, acc[r]);
            }
        }
        for (; k < k1; ++k) {
            float w = wp[k * 64];
#pragma unroll
            for (int r = 0; r < ROWS; ++r) acc[r] = fmaf(xs[r * XSTR + k], w, acc[r]);
        }
    } else {
        // boundary block (rows straddle drug/micr): slow but correct
        for (int k = k0; k < k1; ++k) {
            float wd = WtD[k * 64 + lane];
            float wm = WtM[k * 64 + lane];
#pragma unroll
            for (int r = 0; r < ROWS; ++r) {
                float w = (row0 + r < NDRUG) ? wd : wm;
                acc[r] = fmaf(xs[r * XSTR + k], w, acc[r]);
            }
        }
    }
#pragma unroll
    for (int r = 0; r < ROWS; ++r) part[wave][r][lane] = acc[r];
    __syncthreads();

    // waves 0..3: reduce + epilogue for row r=wave
    if (wave < ROWS) {
        int r = wave;
        int grow = row0 + r;
        if (grow < NROWS) {
            float mx = 0.f, xn2 = 0.f;
#pragma unroll
            for (int w = 0; w < NWAVE; ++w) mx += part[w][r][lane];
#pragma unroll
            for (int w = 0; w < NWAVE; ++w) xn2 += xnps[w][r];
            float mxn2 = wsum(mx * mx);
            float xn = fmaxf(sqrtf(xn2), MINN);
            float mxn = fmaxf(sqrtf(mxn2), MINN);
            float g = mxn / xn * artanh_(xn);
            float t = tanhf(g);
            float res = t * mx / mxn;          // |res| == |t|
            float rn = fabsf(t);
            if (rn > MAXNRM) { res *= MAXNRM / rn; rn = MAXNRM; }
            // mobius_add with hyp_bias
            const float* hb = (grow < NDRUG) ? hbD : hbM;
            float y = hb[lane];
            float y2 = hb2v[(grow < NDRUG) ? 0 : 1];
            float x2 = rn * rn;
            float xy = wsum(res * y);
            float num = (1.0f + 2.0f * xy + y2) * res + (1.0f - x2) * y;
            float den = 1.0f + 2.0f * xy + x2 * y2;
            float v = num / fmaxf(den, MINN);
            float v2 = wsum(v * v);
            float vn = fmaxf(sqrtf(v2), MINN);
            if (vn > MAXNRM) { v *= MAXNRM / vn; vn = MAXNRM; }
            float xt = artanh_(vn) / vn * v;   // logmap0
            liner[(size_t)grow * ODIM + lane] = v;
            xtan[(size_t)grow * ODIM + lane] = xt;
        }
    }
}

// ---- kernel 3: support = adj @ xtan; agg = proj(expmap0); gated HypAct -> h ----
__global__ __launch_bounds__(512) void agg_kernel(
    const float* __restrict__ ADJ, const float* __restrict__ xtan,
    const float* __restrict__ liner, const float* __restrict__ WN /*[128][64]*/,
    const float* __restrict__ biasnode, float* __restrict__ out_h) {
    __shared__ __align__(16) float as[ROWS * XSTR];
    __shared__ float part[NWAVE][ROWS][64];
    __shared__ float zl[ROWS][128];
    int tid = threadIdx.x;
    int wave = tid >> 6, lane = tid & 63;
    int row0 = blockIdx.x * ROWS;

    for (int r = 0; r < ROWS; ++r) {
        int gr = min(row0 + r, NROWS - 1);
        const float2* src = (const float2*)(ADJ + (size_t)gr * INDIM);
        float2* dst = (float2*)&as[r * XSTR];
        for (int c = tid; c < INDIM / 2; c += 512) dst[c] = src[c];
    }
    __syncthreads();

    int k0 = wave * CHUNK;
    int k1 = min(k0 + CHUNK, INDIM);

    float acc[ROWS] = {0.f, 0.f, 0.f, 0.f};
    {
        const float* wp = xtan + lane;
        int k = k0;
        for (; k + 4 <= k1; k += 4) {
            float w0 = wp[(k + 0) * 64];
            float w1 = wp[(k + 1) * 64];
            float w2 = wp[(k + 2) * 64];
            float w3 = wp[(k + 3) * 64];
#pragma unroll
            for (int r = 0; r < ROWS; ++r) {
                float4 xv = *(const float4*)(as + r * XSTR + k);
                acc[r] = fmaf(xv.x, w0, acc[r]);
                acc[r] = fmaf(xv.y, w1, acc[r]);
                acc[r] = fmaf(xv.z, w2, acc[r]);
                acc[r] = fmaf(xv.w, w3, acc[r]);
            }
        }
        for (; k < k1; ++k) {
            float w = wp[k * 64];
#pragma unroll
            for (int r = 0; r < ROWS; ++r) acc[r] = fmaf(as[r * XSTR + k], w, acc[r]);
        }
    }
#pragma unroll
    for (int r = 0; r < ROWS; ++r) part[wave][r][lane] = acc[r];
    __syncthreads();

    if (wave < ROWS) {
        int r = wave;
        int grow = row0 + r;
        if (grow < NROWS) {
            float s = 0.f;
#pragma unroll
            for (int w = 0; w < NWAVE; ++w) s += part[w][r][lane];
            float sn2 = wsum(s * s);
            float sn = fmaxf(sqrtf(sn2), MINN);
            float th = tanhf(sn);
            float agg = th * s / sn;           // expmap0; |agg| == th
            if (th > MAXNRM) agg *= MAXNRM / th;
            float lin = liner[(size_t)grow * ODIM + lane];
            zl[r][lane] = agg;
            zl[r][64 + lane] = lin;
            // delt1 = relu(zf @ WN + biasnode) ; same-wave LDS RAW, no barrier needed
            float d = biasnode[grow];
            const float* w = WN + lane;
#pragma unroll 8
            for (int f = 0; f < 128; ++f) d = fmaf(zl[r][f], w[f * 64], d);
            d = fmaxf(d, 0.0f);
            out_h[(size_t)grow * ODIM + lane] = d * agg + (1.0f - d) * lin;
        }
    }
}

// ---- kernel 4: copy adj into second tuple output ----
__global__ void copy_adj(const float4* __restrict__ src, float4* __restrict__ dst, int n4) {
    for (int i = blockIdx.x * blockDim.x + threadIdx.x; i < n4; i += gridDim.x * blockDim.x)
        dst[i] = src[i];
}

extern "C" void kernel_launch(void* const* d_in, const int* in_sizes, int n_in,
                              void* d_out, int out_size, void* d_ws, size_t ws_size,
                              hipStream_t stream) {
    const float* x   = (const float*)d_in[0];
    const float* adj = (const float*)d_in[1];
    const float* Wd  = (const float*)d_in[2];
    const float* Wm  = (const float*)d_in[3];
    const float* bd  = (const float*)d_in[4];
    const float* bm  = (const float*)d_in[5];
    const float* wn  = (const float*)d_in[6];
    const float* bn  = (const float*)d_in[7];
    float* out = (float*)d_out;
    float* ws  = (float*)d_ws;

    const int WELEMS = ODIM * INDIM;      // 98944
    float* WtD   = ws;
    float* WtM   = ws + WELEMS;
    float* hbD   = ws + 2 * WELEMS;
    float* hbM   = hbD + 64;
    float* hb2   = hbM + 64;
    float* liner = ws + 2 * WELEMS + 192;
    float* xtan  = liner + (size_t)NROWS * ODIM;

    prep_kernel<<<387, 256, 0, stream>>>(Wd, Wm, WtD, WtM);
    bias_kernel<<<1, 128, 0, stream>>>(bd, bm, hbD, hbM, hb2);

    int nblk = (NROWS + ROWS - 1) / ROWS; // 387
    liner_kernel<<<nblk, 512, 0, stream>>>(x, WtD, WtM, hbD, hbM, hb2, liner, xtan);
    agg_kernel<<<nblk, 512, 0, stream>>>(adj, xtan, liner, wn, bn, out);

    int n4 = (NROWS * NROWS) / 4;         // 597529
    copy_adj<<<(n4 + 255) / 256, 256, 0, stream>>>((const float4*)adj,
                                                   (float4*)(out + (size_t)NROWS * ODIM), n4);
}

// Round 3
// 64.797 us; speedup vs baseline: 3.7809x; 1.2668x over previous
//
#include <hip/hip_runtime.h>
#include <math.h>

#define NROWS 1546
#define INDIM 1546
#define ODIM  64
#define NDRUG 1373
#define MINN  1e-15f
#define MAXNRM 0.996f   // (1 - 4e-3)/sqrt(c), c=1

#define KS   8          // K-splits (blocks)
#define CH   194        // K-chunk per split (8*194 >= 1546)
#define RSTR 196        // LDS row stride (196*4 % 16 == 0)

__device__ __forceinline__ float artanh_(float x) {
    x = fminf(fmaxf(x, -1.0f + 1e-7f), 1.0f - 1e-7f);
    return 0.5f * (log1pf(x) - log1pf(-x));
}

__device__ __forceinline__ float wsum(float v) {
#pragma unroll
    for (int off = 32; off > 0; off >>= 1) v += __shfl_xor(v, off, 64);
    return v;
}

// ---- transpose W[64][1546] -> Wt[1546][64] (both matrices) ----
__global__ void prep_kernel(const float* __restrict__ Wd, const float* __restrict__ Wm,
                            float* __restrict__ WtD, float* __restrict__ WtM) {
    int total = ODIM * INDIM;
    for (int i = blockIdx.x * blockDim.x + threadIdx.x; i < total; i += gridDim.x * blockDim.x) {
        int o = i / INDIM;
        int k = i - o * INDIM;
        WtD[k * ODIM + o] = Wd[i];
        WtM[k * ODIM + o] = Wm[i];
    }
}

// ---- hyp_bias = proj(expmap0(bias)), plus |hb|^2 ----
__global__ void bias_kernel(const float* __restrict__ bd, const float* __restrict__ bm,
                            float* __restrict__ hbD, float* __restrict__ hbM,
                            float* __restrict__ hb2) {
    int wave = threadIdx.x >> 6;
    int lane = threadIdx.x & 63;
    const float* b = wave ? bm : bd;
    float v = b[lane];
    float un2 = wsum(v * v);
    float un = fmaxf(sqrtf(un2), MINN);
    float e = tanhf(un) * v / un;
    float en2 = wsum(e * e);
    float en = fmaxf(sqrtf(en2), MINN);
    float scl = (en > MAXNRM) ? (MAXNRM / en) : 1.0f;
    e *= scl;
    float* hb = wave ? hbM : hbD;
    hb[lane] = e;
    if (lane == 0) hb2[wave] = en2 * scl * scl;
}

// ---- phase A1: partial x@Wt over K-chunk + partial row norms ----
__global__ __launch_bounds__(256) void gemmA_liner(
    const float* __restrict__ X, const float* __restrict__ WtD, const float* __restrict__ WtM,
    float* __restrict__ part, float* __restrict__ pnorm) {
    __shared__ __align__(16) float xs[8 * RSTR];
    int tid = threadIdx.x, wave = tid >> 6, lane = tid & 63;
    int row0 = blockIdx.x * 8;
    int kc = blockIdx.y;
    int k0 = kc * CH;
    int len = min(INDIM - k0, CH);

    {   // stage 8 rows x len (32 threads per row)
        int r = tid >> 5, c0 = tid & 31;
        int gr = min(row0 + r, NROWS - 1);
        const float* src = X + (size_t)gr * INDIM + k0;
        for (int c = c0; c < len; c += 32) xs[r * RSTR + c] = src[c];
    }
    __syncthreads();

    int r0 = 2 * wave, r1 = r0 + 1;
    int g0 = row0 + r0, g1 = g0 + 1;

    {   // partial squared norms
        float p0 = 0.f, p1 = 0.f;
        for (int c = lane; c < len; c += 64) {
            float a = xs[r0 * RSTR + c]; p0 = fmaf(a, a, p0);
            float b = xs[r1 * RSTR + c]; p1 = fmaf(b, b, p1);
        }
        p0 = wsum(p0); p1 = wsum(p1);
        if (lane == 0) {
            if (g0 < NROWS) pnorm[g0 * KS + kc] = p0;
            if (g1 < NROWS) pnorm[g1 * KS + kc] = p1;
        }
    }

    float acc0 = 0.f, acc1 = 0.f;
    bool u = (g0 < NDRUG) == (g1 < NDRUG);
    if (u) {
        const float* wp = ((g0 < NDRUG) ? WtD : WtM) + (size_t)k0 * 64 + lane;
        int kk = 0;
        for (; kk + 4 <= len; kk += 4) {
            float w0 = wp[(kk + 0) * 64];
            float w1 = wp[(kk + 1) * 64];
            float w2 = wp[(kk + 2) * 64];
            float w3 = wp[(kk + 3) * 64];
            float4 a = *(const float4*)(xs + r0 * RSTR + kk);
            float4 b = *(const float4*)(xs + r1 * RSTR + kk);
            acc0 = fmaf(a.x, w0, acc0); acc0 = fmaf(a.y, w1, acc0);
            acc0 = fmaf(a.z, w2, acc0); acc0 = fmaf(a.w, w3, acc0);
            acc1 = fmaf(b.x, w0, acc1); acc1 = fmaf(b.y, w1, acc1);
            acc1 = fmaf(b.z, w2, acc1); acc1 = fmaf(b.w, w3, acc1);
        }
        for (; kk < len; ++kk) {
            float w = wp[kk * 64];
            acc0 = fmaf(xs[r0 * RSTR + kk], w, acc0);
            acc1 = fmaf(xs[r1 * RSTR + kk], w, acc1);
        }
    } else {
        const float* wp0 = ((g0 < NDRUG) ? WtD : WtM) + (size_t)k0 * 64 + lane;
        const float* wp1 = ((g1 < NDRUG) ? WtD : WtM) + (size_t)k0 * 64 + lane;
        for (int kk = 0; kk < len; ++kk) {
            acc0 = fmaf(xs[r0 * RSTR + kk], wp0[kk * 64], acc0);
            acc1 = fmaf(xs[r1 * RSTR + kk], wp1[kk * 64], acc1);
        }
    }
    if (g0 < NROWS) part[(size_t)g0 * (KS * 64) + kc * 64 + lane] = acc0;
    if (g1 < NROWS) part[(size_t)g1 * (KS * 64) + kc * 64 + lane] = acc1;
}

// ---- phase A2: partial adj@xtan over K-chunk ----
__global__ __launch_bounds__(256) void gemmA_agg(
    const float* __restrict__ ADJ, const float* __restrict__ xtan,
    float* __restrict__ part) {
    __shared__ __align__(16) float xs[8 * RSTR];
    int tid = threadIdx.x, wave = tid >> 6, lane = tid & 63;
    int row0 = blockIdx.x * 8;
    int kc = blockIdx.y;
    int k0 = kc * CH;
    int len = min(INDIM - k0, CH);

    {
        int r = tid >> 5, c0 = tid & 31;
        int gr = min(row0 + r, NROWS - 1);
        const float* src = ADJ + (size_t)gr * INDIM + k0;
        for (int c = c0; c < len; c += 32) xs[r * RSTR + c] = src[c];
    }
    __syncthreads();

    int r0 = 2 * wave, r1 = r0 + 1;
    int g0 = row0 + r0, g1 = g0 + 1;

    float acc0 = 0.f, acc1 = 0.f;
    {
        const float* wp = xtan + (size_t)k0 * 64 + lane;
        int kk = 0;
        for (; kk + 4 <= len; kk += 4) {
            float w0 = wp[(kk + 0) * 64];
            float w1 = wp[(kk + 1) * 64];
            float w2 = wp[(kk + 2) * 64];
            float w3 = wp[(kk + 3) * 64];
            float4 a = *(const float4*)(xs + r0 * RSTR + kk);
            float4 b = *(const float4*)(xs + r1 * RSTR + kk);
            acc0 = fmaf(a.x, w0, acc0); acc0 = fmaf(a.y, w1, acc0);
            acc0 = fmaf(a.z, w2, acc0); acc0 = fmaf(a.w, w3, acc0);
            acc1 = fmaf(b.x, w0, acc1); acc1 = fmaf(b.y, w1, acc1);
            acc1 = fmaf(b.z, w2, acc1); acc1 = fmaf(b.w, w3, acc1);
        }
        for (; kk < len; ++kk) {
            float w = wp[kk * 64];
            acc0 = fmaf(xs[r0 * RSTR + kk], w, acc0);
            acc1 = fmaf(xs[r1 * RSTR + kk], w, acc1);
        }
    }
    if (g0 < NROWS) part[(size_t)g0 * (KS * 64) + kc * 64 + lane] = acc0;
    if (g1 < NROWS) part[(size_t)g1 * (KS * 64) + kc * 64 + lane] = acc1;
}

// ---- phase B1: reduce partials + hyperbolic epilogue -> liner, xtan ----
__global__ __launch_bounds__(512) void linerB(
    const float* __restrict__ part, const float* __restrict__ pnorm,
    const float* __restrict__ hbD, const float* __restrict__ hbM, const float* __restrict__ hb2v,
    float* __restrict__ liner, float* __restrict__ xtan) {
    int wave = threadIdx.x >> 6, lane = threadIdx.x & 63;
    int grow = blockIdx.x * 8 + wave;
    if (grow >= NROWS) return;
    float mx = 0.f, xn2 = 0.f;
#pragma unroll
    for (int kc = 0; kc < KS; ++kc) mx += part[(size_t)grow * (KS * 64) + kc * 64 + lane];
#pragma unroll
    for (int kc = 0; kc < KS; ++kc) xn2 += pnorm[grow * KS + kc];

    float mxn2 = wsum(mx * mx);
    float xn = fmaxf(sqrtf(xn2), MINN);
    float mxn = fmaxf(sqrtf(mxn2), MINN);
    float g = mxn / xn * artanh_(xn);
    float t = tanhf(g);
    float res = t * mx / mxn;              // |res| == |t|
    float rn = fabsf(t);
    if (rn > MAXNRM) { res *= MAXNRM / rn; rn = MAXNRM; }
    const float* hb = (grow < NDRUG) ? hbD : hbM;
    float y = hb[lane];
    float y2 = hb2v[(grow < NDRUG) ? 0 : 1];
    float x2 = rn * rn;
    float xy = wsum(res * y);
    float num = (1.0f + 2.0f * xy + y2) * res + (1.0f - x2) * y;
    float den = 1.0f + 2.0f * xy + x2 * y2;
    float v = num / fmaxf(den, MINN);
    float v2 = wsum(v * v);
    float vn = fmaxf(sqrtf(v2), MINN);
    if (vn > MAXNRM) { v *= MAXNRM / vn; vn = MAXNRM; }
    float xt = artanh_(vn) / vn * v;       // logmap0
    liner[(size_t)grow * ODIM + lane] = v;
    xtan[(size_t)grow * ODIM + lane] = xt;
}

// ---- phase B2: reduce partials + expmap0/proj + gated HypAct -> h ----
__global__ __launch_bounds__(512) void aggB(
    const float* __restrict__ part, const float* __restrict__ liner,
    const float* __restrict__ WN /*[128][64]*/, const float* __restrict__ biasnode,
    float* __restrict__ out_h) {
    __shared__ float zl[8][128];
    int wave = threadIdx.x >> 6, lane = threadIdx.x & 63;
    int grow = blockIdx.x * 8 + wave;
    if (grow >= NROWS) return;
    float s = 0.f;
#pragma unroll
    for (int kc = 0; kc < KS; ++kc) s += part[(size_t)grow * (KS * 64) + kc * 64 + lane];
    float sn2 = wsum(s * s);
    float sn = fmaxf(sqrtf(sn2), MINN);
    float th = tanhf(sn);
    float agg = th * s / sn;               // expmap0; |agg| == th
    if (th > MAXNRM) agg *= MAXNRM / th;
    float lin = liner[(size_t)grow * ODIM + lane];
    zl[wave][lane] = agg;
    zl[wave][64 + lane] = lin;
    float d = biasnode[grow];
    const float* w = WN + lane;
#pragma unroll 8
    for (int f = 0; f < 128; ++f) d = fmaf(zl[wave][f], w[f * 64], d);
    d = fmaxf(d, 0.0f);
    out_h[(size_t)grow * ODIM + lane] = d * agg + (1.0f - d) * lin;
}

// ---- copy adj into second tuple output (overwrites partial scratch) ----
__global__ void copy_adj(const float4* __restrict__ src, float4* __restrict__ dst, int n4) {
    for (int i = blockIdx.x * blockDim.x + threadIdx.x; i < n4; i += gridDim.x * blockDim.x)
        dst[i] = src[i];
}

extern "C" void kernel_launch(void* const* d_in, const int* in_sizes, int n_in,
                              void* d_out, int out_size, void* d_ws, size_t ws_size,
                              hipStream_t stream) {
    const float* x   = (const float*)d_in[0];
    const float* adj = (const float*)d_in[1];
    const float* Wd  = (const float*)d_in[2];
    const float* Wm  = (const float*)d_in[3];
    const float* bd  = (const float*)d_in[4];
    const float* bm  = (const float*)d_in[5];
    const float* wn  = (const float*)d_in[6];
    const float* bn  = (const float*)d_in[7];
    float* out = (float*)d_out;
    float* ws  = (float*)d_ws;

    const int WELEMS = ODIM * INDIM;      // 98944
    float* WtD   = ws;
    float* WtM   = ws + WELEMS;
    float* hbD   = ws + 2 * WELEMS;
    float* hbM   = hbD + 64;
    float* hb2   = hbM + 64;
    float* liner = ws + 2 * WELEMS + 192;
    float* xtan  = liner + WELEMS;
    float* pnorm = xtan + WELEMS;         // 1546*8 floats

    // partial sums live in the adj-output region; copy_adj overwrites them last
    float* part = out + WELEMS;           // needs 1546*8*64 = 791552 <= 1546*1546

    prep_kernel<<<387, 256, 0, stream>>>(Wd, Wm, WtD, WtM);
    bias_kernel<<<1, 128, 0, stream>>>(bd, bm, hbD, hbM, hb2);

    dim3 gA(194, KS);
    gemmA_liner<<<gA, 256, 0, stream>>>(x, WtD, WtM, part, pnorm);
    linerB<<<194, 512, 0, stream>>>(part, pnorm, hbD, hbM, hb2, liner, xtan);
    gemmA_agg<<<gA, 256, 0, stream>>>(adj, xtan, part);
    aggB<<<194, 512, 0, stream>>>(part, liner, wn, bn, out);

    int n4 = (NROWS * NROWS) / 4;         // 597529
    copy_adj<<<(n4 + 255) / 256, 256, 0, stream>>>((const float4*)adj,
                                                   (float4*)(out + WELEMS), n4);
}